// Round 6
// baseline (137.012 us; speedup 1.0000x reference)
//
#include <hip/hip_runtime.h>
#include <stdint.h>

#define N 8192
#define D 256          // elements per row == bytes per fp8 row
#define INV_T 20.0f
#define LOG2E 1.44269504088896340736f
#define BM 128
#define BN 128
#define NXB 64         // col-blocks (N/BN)

typedef __attribute__((ext_vector_type(16))) float f32x16;
typedef __attribute__((ext_vector_type(4))) int i32x4;
typedef __attribute__((ext_vector_type(8))) int i32x8;

typedef __attribute__((address_space(3))) uint32_t lds_u32;
typedef __attribute__((address_space(1))) const uint32_t gbl_u32;

// Raw v_exp_f32 (2^x). Library exp2f carries a multi-instruction guard for
// |x|>~126; our args are bounded (|x| <= ~62), so the raw trans op is safe.
static __device__ __forceinline__ float fast_exp2(float x) {
  float r;
  asm("v_exp_f32 %0, %1" : "=v"(r) : "v"(x));
  return r;
}

// DPP-fused butterfly add levels (VALU, replaces ds_swizzle+add):
//   xor1 = quad_perm [1,0,3,2] (0xB1), xor2 = quad_perm [2,3,0,1] (0x4E);
//   after those, quads are uniform, so row_half_mirror (0x141) == xor4 and
//   row_mirror (0x140) == xor8. Same pairwise tree as __shfl_xor -> bit-identical.
#define DPP_ADD(v, ctrl)                                                      \
  ((v) + __builtin_bit_cast(float, __builtin_amdgcn_update_dpp(               \
             0, __builtin_bit_cast(int, (v)), (ctrl), 0xf, 0xf, true)))

// Kernel 1: per-row fp32 normalize -> fp8 e4m3 copies (HW cvt, OCP on gfx950);
// c[i] = (e_i . p_i)/T exact fp32.  Also zeroes the reduce kernel's done-counter
// (stream-serialized before it; makes the last-block-done trick replay-safe).
__global__ __launch_bounds__(256) void normalize_kernel(
    const float* __restrict__ e, const float* __restrict__ p, const float* __restrict__ n,
    uint32_t* __restrict__ eb, uint32_t* __restrict__ pb, uint32_t* __restrict__ nb,
    float* __restrict__ cbuf, uint32_t* __restrict__ counter) {
  const int tid = threadIdx.x;
  const int wave = tid >> 6, lane = tid & 63;
  const int row = blockIdx.x * 4 + wave;          // one wave per row

  if (blockIdx.x == 0 && tid == 0) *counter = 0u;

  const float4 ev = ((const float4*)(e + (size_t)row * D))[lane];
  const float4 pv = ((const float4*)(p + (size_t)row * D))[lane];
  const float4 nv = ((const float4*)(n + (size_t)row * D))[lane];

  float sse = ev.x*ev.x + ev.y*ev.y + ev.z*ev.z + ev.w*ev.w;
  float ssp = pv.x*pv.x + pv.y*pv.y + pv.z*pv.z + pv.w*pv.w;
  float ssn = nv.x*nv.x + nv.y*nv.y + nv.z*nv.z + nv.w*nv.w;
  float dep = ev.x*pv.x + ev.y*pv.y + ev.z*pv.z + ev.w*pv.w;
#pragma unroll
  for (int m = 1; m < 64; m <<= 1) {
    sse += __shfl_xor(sse, m);
    ssp += __shfl_xor(ssp, m);
    ssn += __shfl_xor(ssn, m);
    dep += __shfl_xor(dep, m);
  }
  const float se = 1.0f / fmaxf(sqrtf(sse), 1e-8f);
  const float sp = 1.0f / fmaxf(sqrtf(ssp), 1e-8f);
  const float sn = 1.0f / fmaxf(sqrtf(ssn), 1e-8f);

  int ue = __builtin_amdgcn_cvt_pk_fp8_f32(ev.x*se, ev.y*se, 0, false);
  ue     = __builtin_amdgcn_cvt_pk_fp8_f32(ev.z*se, ev.w*se, ue, true);
  int up = __builtin_amdgcn_cvt_pk_fp8_f32(pv.x*sp, pv.y*sp, 0, false);
  up     = __builtin_amdgcn_cvt_pk_fp8_f32(pv.z*sp, pv.w*sp, up, true);
  int un = __builtin_amdgcn_cvt_pk_fp8_f32(nv.x*sn, nv.y*sn, 0, false);
  un     = __builtin_amdgcn_cvt_pk_fp8_f32(nv.z*sn, nv.w*sn, un, true);
  eb[row * 64 + lane] = (uint32_t)ue;             // 64 uints = 256 fp8 bytes per row
  pb[row * 64 + lane] = (uint32_t)up;
  nb[row * 64 + lane] = (uint32_t)un;

  if (lane == 0) cbuf[row] = dep * se * sp * INV_T;
}

// Kernel 2: 128x128-tile fp8 GEMM (X @ Y^T) with fused exp row-sums.
// Round-5 structure (58 us, 0 bank conflicts, VGPR 52, no spill) + occupancy:
//  - B staged full-K (32 KB, single buffer, ONE barrier) via global_load_lds,
//    16-slot XOR layout: group gg of row r at slot gg^(r&15) (read XORs again
//    -> canonical K-order; involution). Measured conflict-free.
//  - A direct to registers (8 x dwordx4 per lane; block footprint 32 KB, L1/L2).
//  - MX-scaled MFMA 32x32x64_f8f6f4 (fmt 0 = e4m3, unit scales): bit-exact vs
//    non-scaled fp8 (rounds 1-5, absmax 0) at 2x rate.
//  - Raw v_exp_f32 + XOR-folded B addresses (round 5).
//  - NEW: __launch_bounds__(256,4) -> 4 blocks/CU (LDS 4x33.3=133 KB < 160;
//    VGPR 52 << 128 cap). 8192 blocks / 1024 resident = EXACTLY 8 dispatch
//    batches (no tail). Round-5 counters showed no pipe >50% -> latency-bound;
//    a 4th independent block per CU fills the bubbles.
//  - NEW: s_setprio(1) around the MFMA K-loop (T5): with 4 drifting blocks the
//    CU has wave role diversity (stage vs K-loop vs epilogue) - the regime
//    where setprio measurably helps.
__global__ __launch_bounds__(256, 4) void simexp_kernel(
    const uint8_t* __restrict__ eb, const uint8_t* __restrict__ pb,
    const uint8_t* __restrict__ nb, const float* __restrict__ cbuf,
    float* __restrict__ part) {
  __shared__ uint8_t Bs[BN * D];    // 32 KB, full-K B tile (swizzled)
  __shared__ float cs[BM];          // 512 B

  const int z = blockIdx.z;
  const uint8_t* __restrict__ A = z ? pb : eb;
  const uint8_t* __restrict__ B = z ? eb : nb;

  const int tid = threadIdx.x;
  const int wave = tid >> 6, lane = tid & 63;
  const int lane31 = lane & 31, half = lane >> 5;
  const int rowTile = blockIdx.x * BM, colblk = blockIdx.y;
  const int colTile = colblk * BN;

  // ---- stage B (full K): 2048 16B chunks, 8 per thread, coalesced ----
#pragma unroll
  for (int i = 0; i < 8; ++i) {
    const int c = i * 256 + tid, r = c >> 4, sl = c & 15;
    const int gg = sl ^ (r & 15);               // swizzled SOURCE group
    __builtin_amdgcn_global_load_lds(
        (gbl_u32*)(B + (size_t)(colTile + r) * D + gg * 16),
        (lds_u32*)&Bs[c * 16], 16, 0, 0);
  }

  // ---- A direct to registers: this lane's row, its K-half, all 4 K-steps ----
  const int arow = rowTile + wave * 32 + lane31;
  const uint8_t* __restrict__ Arow = A + (size_t)arow * D + half * 32;
  i32x8 afr[4];
#pragma unroll
  for (int s = 0; s < 4; ++s) {
    const i32x4 lo = *(const i32x4*)(Arow + s * 64);
    const i32x4 hi = *(const i32x4*)(Arow + s * 64 + 16);
    afr[s] = (i32x8){lo[0], lo[1], lo[2], lo[3], hi[0], hi[1], hi[2], hi[3]};
  }

  if (tid < BM) cs[tid] = cbuf[rowTile + tid] * LOG2E;

  // per-ni XOR-folded B fragment base addresses (byte offsets into Bs)
  int bbase[4];
#pragma unroll
  for (int ni = 0; ni < 4; ++ni) {
    const int cl = ni * 32 + lane31;
    bbase[ni] = (cl << 8) ^ ((cl & 15) << 4) ^ (half << 5);
  }

  f32x16 acc[4];
#pragma unroll
  for (int ni = 0; ni < 4; ++ni)
#pragma unroll
    for (int r = 0; r < 16; ++r) acc[ni][r] = 0.0f;

  __syncthreads();   // the ONLY barrier: B tile + cs visible

  // ---- K loop: 4 steps of K=64, zero barriers, compiler free to pipeline ----
  __builtin_amdgcn_s_setprio(1);
#pragma unroll
  for (int s = 0; s < 4; ++s) {
#pragma unroll
    for (int ni = 0; ni < 4; ++ni) {
      const int alo = bbase[ni] ^ (s << 6);     // 1 v_xor (s<<6 is inline const)
      const i32x4 blo = *(const i32x4*)&Bs[alo];
      const i32x4 bhi = *(const i32x4*)&Bs[alo ^ 16];
      const i32x8 b = (i32x8){blo[0], blo[1], blo[2], blo[3],
                              bhi[0], bhi[1], bhi[2], bhi[3]};
      acc[ni] = __builtin_amdgcn_mfma_scale_f32_32x32x64_f8f6f4(
          afr[s], b, acc[ni],
          0 /*A fmt fp8*/, 0 /*B fmt fp8*/,
          0, 0x7F7F7F7F /*scaleA=1*/, 0, 0x7F7F7F7F /*scaleB=1*/);
    }
  }
  __builtin_amdgcn_s_setprio(0);

  // ---- epilogue: exp2 + row-sum over this wave's 128 cols ----
  // 32x32 C/D: col=lane&31, row=(reg&3)+8*(reg>>2)+4*(lane>>5) (m74/m101).
  const float K2 = INV_T * LOG2E;
#pragma unroll
  for (int reg = 0; reg < 16; ++reg) {
    const int rlocal = (reg & 3) + 8 * (reg >> 2) + 4 * half;
    const int rowl = wave * 32 + rlocal;
    const float cv = cs[rowl];
    float v = fast_exp2(acc[0][reg] * K2 - cv) + fast_exp2(acc[1][reg] * K2 - cv) +
              fast_exp2(acc[2][reg] * K2 - cv) + fast_exp2(acc[3][reg] * K2 - cv);
    v = DPP_ADD(v, 0xB1);    // xor1: quad_perm [1,0,3,2]
    v = DPP_ADD(v, 0x4E);    // xor2: quad_perm [2,3,0,1]
    v = DPP_ADD(v, 0x141);   // xor4: row_half_mirror
    v = DPP_ADD(v, 0x140);   // xor8: row_mirror
    v += __builtin_bit_cast(float, __builtin_amdgcn_ds_swizzle(
             __builtin_bit_cast(int, v), 0x401F));  // xor16
    if (lane31 == 0)
      part[((size_t)(z * NXB + colblk)) * N + rowTile + rowl] = v;
  }
}

// Kernel 3 (fused): per-row sum of 64 partials -> log/log1p -> 256 block
// partials -> last-block-done final 256-way sum -> mean loss.
// Counter is zeroed by normalize_kernel each launch (replay-safe); the final
// sum tree is deterministic (fixed block reads the partials array).
__global__ __launch_bounds__(64) void reduce_kernel(const float* __restrict__ part,
                                                    float* __restrict__ partials,
                                                    uint32_t* __restrict__ counter,
                                                    float* __restrict__ out) {
  const int bid = blockIdx.x;              // 256 blocks
  const int z = bid >> 7;                  // 128 blocks per z-slice
  const int row = (bid & 127) * 64 + threadIdx.x;
  float s = 0.0f;
#pragma unroll 8
  for (int x = 0; x < NXB; ++x)
    s += part[((size_t)(z * NXB + x)) * N + row];
  float val = z ? logf(s) : log1pf(s);
#pragma unroll
  for (int m = 1; m < 64; m <<= 1) val += __shfl_xor(val, m);
  if (threadIdx.x == 0) partials[bid] = val;

  // last-block-done: device-scope release, count, winner does the final sum.
  __threadfence();
  __shared__ bool lastb;
  if (threadIdx.x == 0)
    lastb = (atomicAdd(counter, 1u) == 255u);
  __syncthreads();
  if (lastb) {
    __threadfence();   // acquire: make all partials visible across XCDs
    const int t = threadIdx.x;
    float v = partials[t] + partials[t + 64] + partials[t + 128] + partials[t + 192];
#pragma unroll
    for (int m = 1; m < 64; m <<= 1) v += __shfl_xor(v, m);
    if (t == 0) out[0] = v * (1.0f / (float)N);
  }
}

extern "C" void kernel_launch(void* const* d_in, const int* in_sizes, int n_in,
                              void* d_out, int out_size, void* d_ws, size_t ws_size,
                              hipStream_t stream) {
  const float* e = (const float*)d_in[0];
  const float* p = (const float*)d_in[1];
  const float* n = (const float*)d_in[2];

  char* w = (char*)d_ws;
  uint8_t* eb = (uint8_t*)w;                                     // 2 MB
  uint8_t* pb = eb + (size_t)N * D;                              // 2 MB
  uint8_t* nb = pb + (size_t)N * D;                              // 2 MB
  float* cbuf = (float*)(nb + (size_t)N * D);                    // 32 KB
  float* part = cbuf + N;                                        // 4 MB
  float* partials = part + (size_t)2 * NXB * N;                  // 1 KB
  uint32_t* counter = (uint32_t*)(partials + 256);               // 4 B

  normalize_kernel<<<N / 4, 256, 0, stream>>>(e, p, n, (uint32_t*)eb, (uint32_t*)pb,
                                              (uint32_t*)nb, cbuf, counter);
  simexp_kernel<<<dim3(N / BM, N / BN, 2), 256, 0, stream>>>(eb, pb, nb, cbuf, part);
  reduce_kernel<<<256, 64, 0, stream>>>(part, partials, counter, (float*)d_out);
}

// Round 7
// 128.252 us; speedup vs baseline: 1.0683x; 1.0683x over previous
//
#include <hip/hip_runtime.h>
#include <stdint.h>

#define N 8192
#define D 256          // elements per row == bytes per fp8 row
#define INV_T 20.0f
#define LOG2E 1.44269504088896340736f
#define BM 128
#define BN 128
#define NCHUNK 4       // col-chunks (grid.x)
#define NT 16          // col-tiles per chunk; NCHUNK*NT*BN == N

typedef __attribute__((ext_vector_type(16))) float f32x16;
typedef __attribute__((ext_vector_type(4))) int i32x4;
typedef __attribute__((ext_vector_type(8))) int i32x8;

typedef __attribute__((address_space(3))) uint32_t lds_u32;
typedef __attribute__((address_space(1))) const uint32_t gbl_u32;

// Raw v_exp_f32 (2^x). Library exp2f carries a multi-instruction guard for
// |x|>~126; our args are bounded, so the raw trans op is safe (verified r5).
static __device__ __forceinline__ float fast_exp2(float x) {
  float r;
  asm("v_exp_f32 %0, %1" : "=v"(r) : "v"(x));
  return r;
}

// DPP-fused butterfly add levels (bit-identical to __shfl_xor tree, r4/r5).
#define DPP_ADD(v, ctrl)                                                      \
  ((v) + __builtin_bit_cast(float, __builtin_amdgcn_update_dpp(               \
             0, __builtin_bit_cast(int, (v)), (ctrl), 0xf, 0xf, true)))

// Kernel 1: per-row fp32 normalize -> fp8 e4m3 copies (HW cvt, OCP on gfx950);
// c[i] = (e_i . p_i)/T exact fp32.
__global__ __launch_bounds__(256) void normalize_kernel(
    const float* __restrict__ e, const float* __restrict__ p, const float* __restrict__ n,
    uint32_t* __restrict__ eb, uint32_t* __restrict__ pb, uint32_t* __restrict__ nb,
    float* __restrict__ cbuf) {
  const int tid = threadIdx.x;
  const int wave = tid >> 6, lane = tid & 63;
  const int row = blockIdx.x * 4 + wave;          // one wave per row

  const float4 ev = ((const float4*)(e + (size_t)row * D))[lane];
  const float4 pv = ((const float4*)(p + (size_t)row * D))[lane];
  const float4 nv = ((const float4*)(n + (size_t)row * D))[lane];

  float sse = ev.x*ev.x + ev.y*ev.y + ev.z*ev.z + ev.w*ev.w;
  float ssp = pv.x*pv.x + pv.y*pv.y + pv.z*pv.z + pv.w*pv.w;
  float ssn = nv.x*nv.x + nv.y*nv.y + nv.z*nv.z + nv.w*nv.w;
  float dep = ev.x*pv.x + ev.y*pv.y + ev.z*pv.z + ev.w*pv.w;
#pragma unroll
  for (int m = 1; m < 64; m <<= 1) {
    sse += __shfl_xor(sse, m);
    ssp += __shfl_xor(ssp, m);
    ssn += __shfl_xor(ssn, m);
    dep += __shfl_xor(dep, m);
  }
  const float se = 1.0f / fmaxf(sqrtf(sse), 1e-8f);
  const float sp = 1.0f / fmaxf(sqrtf(ssp), 1e-8f);
  const float sn = 1.0f / fmaxf(sqrtf(ssn), 1e-8f);

  int ue = __builtin_amdgcn_cvt_pk_fp8_f32(ev.x*se, ev.y*se, 0, false);
  ue     = __builtin_amdgcn_cvt_pk_fp8_f32(ev.z*se, ev.w*se, ue, true);
  int up = __builtin_amdgcn_cvt_pk_fp8_f32(pv.x*sp, pv.y*sp, 0, false);
  up     = __builtin_amdgcn_cvt_pk_fp8_f32(pv.z*sp, pv.w*sp, up, true);
  int un = __builtin_amdgcn_cvt_pk_fp8_f32(nv.x*sn, nv.y*sn, 0, false);
  un     = __builtin_amdgcn_cvt_pk_fp8_f32(nv.z*sn, nv.w*sn, un, true);
  eb[row * 64 + lane] = (uint32_t)ue;             // 64 uints = 256 fp8 bytes per row
  pb[row * 64 + lane] = (uint32_t)up;
  nb[row * 64 + lane] = (uint32_t)un;

  if (lane == 0) cbuf[row] = dep * se * sp * INV_T;
}

// Kernel 2: PERSISTENT column-walk fp8 GEMM (X @ Y^T) with fused exp row-sums.
// 512 blocks (2/CU, one dispatch batch, no tail); each block keeps rows
// [rowTile,rowTile+128) and walks 16 col-tiles of its chunk:
//  - B double-buffered (2 x 32 KB full-K tiles) with counted vmcnt: raw
//    s_barrier + "s_waitcnt vmcnt(8)" -> exactly one B tile in flight; B(t+1)
//    is issued 2 iterations before it's waited on. In-order vmem retirement
//    makes vmcnt(8) also drain the prologue A/cv loads (oldest-first, m135).
//  - 16-slot XOR LDS layout (r1-r5, measured 0 bank conflicts): group gg of
//    row r at slot gg^(r&15); read XORs again (involution -> canonical K).
//    Buffer parity folded in by XOR of bit 15 (bbase has bit 15 clear).
//  - A-frags (32 VGPR) + cv diag terms (16 VGPR, direct cbuf broadcast loads)
//    held for all 16 tiles; cross-lane DPP reduce + part store ONCE per block.
//  - MX-scaled MFMA 32x32x64_f8f6f4 (e4m3, unit scales): bit-exact at 2x rate.
// Regs ~90 arch + 64 AGPR at 2 waves/SIMD (cap 256) -> no spill (sentinel:
// WRITE_SIZE stays ~4 MB). LDS 64 KB -> 2 blocks/CU.
__global__ __launch_bounds__(256, 2) void simexp_kernel(
    const uint8_t* __restrict__ eb, const uint8_t* __restrict__ pb,
    const uint8_t* __restrict__ nb, const float* __restrict__ cbuf,
    float* __restrict__ part) {
  __shared__ uint8_t Bs[2][BN * D];   // 64 KB

  const int z = blockIdx.z;
  const uint8_t* __restrict__ A = z ? pb : eb;
  const uint8_t* __restrict__ B = z ? eb : nb;

  const int tid = threadIdx.x;
  const int wave = tid >> 6, lane = tid & 63;
  const int lane31 = lane & 31, half = lane >> 5;
  const int chunk = blockIdx.x;
  const int rowTile = blockIdx.y * BM;
  const int colblk0 = chunk * NT;

#define STAGEB(buf, cblk)                                                     \
  do {                                                                        \
    const uint8_t* __restrict__ Bsrc = B + (size_t)(cblk) * (BN * D);         \
    _Pragma("unroll") for (int i = 0; i < 8; ++i) {                           \
      const int c = i * 256 + tid, r = c >> 4, sl = c & 15;                   \
      const int gg = sl ^ (r & 15);                                           \
      __builtin_amdgcn_global_load_lds(                                       \
          (gbl_u32*)(Bsrc + (size_t)r * D + gg * 16),                         \
          (lds_u32*)&Bs[buf][c * 16], 16, 0, 0);                              \
    }                                                                         \
  } while (0)

  // ---- prologue: A-frags + cv to registers, then B0/B1 staging ----
  const int arow = rowTile + wave * 32 + lane31;
  const uint8_t* __restrict__ Arow = A + (size_t)arow * D + half * 32;
  i32x8 afr[4];
#pragma unroll
  for (int s = 0; s < 4; ++s) {
    const i32x4 lo = *(const i32x4*)(Arow + s * 64);
    const i32x4 hi = *(const i32x4*)(Arow + s * 64 + 16);
    afr[s] = (i32x8){lo[0], lo[1], lo[2], lo[3], hi[0], hi[1], hi[2], hi[3]};
  }
  float cv[16];   // diag term per acc reg (L1 broadcast loads, 128 addrs/block)
#pragma unroll
  for (int reg = 0; reg < 16; ++reg)
    cv[reg] = cbuf[rowTile + wave * 32 + (reg & 3) + 8 * (reg >> 2) + 4 * half] * LOG2E;

  STAGEB(0, colblk0 + 0);
  STAGEB(1, colblk0 + 1);
  __builtin_amdgcn_sched_barrier(0);   // pin prologue loads above the loop

  // per-ni XOR-folded B fragment base addresses (bit 15 = buffer parity, clear)
  int bbase[4];
#pragma unroll
  for (int ni = 0; ni < 4; ++ni) {
    const int cl = ni * 32 + lane31;
    bbase[ni] = (cl << 8) ^ ((cl & 15) << 4) ^ (half << 5);
  }

  float sums[16];
#pragma unroll
  for (int reg = 0; reg < 16; ++reg) sums[reg] = 0.0f;

  const uint8_t* __restrict__ bs = &Bs[0][0];
  const float K2 = INV_T * LOG2E;

#define TILE_BODY(t, VCNT)                                                    \
  do {                                                                        \
    asm volatile("s_waitcnt vmcnt(" #VCNT ")" ::: "memory");                  \
    __builtin_amdgcn_s_barrier();                                             \
    __builtin_amdgcn_sched_barrier(0);                                        \
    const int bpar = ((t) & 1) << 15;                                         \
    f32x16 acc[4];                                                            \
    _Pragma("unroll") for (int ni = 0; ni < 4; ++ni)                          \
      _Pragma("unroll") for (int r = 0; r < 16; ++r) acc[ni][r] = 0.0f;       \
    _Pragma("unroll") for (int s = 0; s < 4; ++s) {                           \
      _Pragma("unroll") for (int ni = 0; ni < 4; ++ni) {                      \
        const int alo = (bbase[ni] ^ bpar) ^ (s << 6);                        \
        const i32x4 blo = *(const i32x4*)&bs[alo];                            \
        const i32x4 bhi = *(const i32x4*)&bs[alo ^ 16];                       \
        const i32x8 b = (i32x8){blo[0], blo[1], blo[2], blo[3],               \
                                bhi[0], bhi[1], bhi[2], bhi[3]};              \
        acc[ni] = __builtin_amdgcn_mfma_scale_f32_32x32x64_f8f6f4(            \
            afr[s], b, acc[ni], 0, 0, 0, 0x7F7F7F7F, 0, 0x7F7F7F7F);          \
      }                                                                       \
    }                                                                         \
    __builtin_amdgcn_sched_barrier(0);                                        \
    __builtin_amdgcn_s_barrier();   /* all waves done reading buf (t&1) */    \
    __builtin_amdgcn_sched_barrier(0);                                        \
    if ((t) + 2 < NT) STAGEB((t) & 1, colblk0 + (t) + 2);                     \
    _Pragma("unroll") for (int reg = 0; reg < 16; ++reg) {                    \
      sums[reg] += fast_exp2(acc[0][reg] * K2 - cv[reg]) +                    \
                   fast_exp2(acc[1][reg] * K2 - cv[reg]) +                    \
                   fast_exp2(acc[2][reg] * K2 - cv[reg]) +                    \
                   fast_exp2(acc[3][reg] * K2 - cv[reg]);                     \
    }                                                                         \
  } while (0)

#pragma unroll 1
  for (int t = 0; t < NT - 1; ++t) TILE_BODY(t, 8);
  TILE_BODY(NT - 1, 0);
#undef TILE_BODY
#undef STAGEB

  // ---- once per block: 32-lane butterfly reduce + store ----
#pragma unroll
  for (int reg = 0; reg < 16; ++reg) {
    float v = sums[reg];
    v = DPP_ADD(v, 0xB1);    // xor1: quad_perm [1,0,3,2]
    v = DPP_ADD(v, 0x4E);    // xor2: quad_perm [2,3,0,1]
    v = DPP_ADD(v, 0x141);   // xor4: row_half_mirror
    v = DPP_ADD(v, 0x140);   // xor8: row_mirror
    v += __builtin_bit_cast(float, __builtin_amdgcn_ds_swizzle(
             __builtin_bit_cast(int, v), 0x401F));  // xor16
    if (lane31 == 0) {
      const int rowl = wave * 32 + (reg & 3) + 8 * (reg >> 2) + 4 * half;
      part[((size_t)(z * NCHUNK + chunk)) * N + rowTile + rowl] = v;
    }
  }
}

// Kernel 3: per-row sum of 4 partials -> log/log1p -> 256 block partials.
__global__ __launch_bounds__(64) void reduce1_kernel(const float* __restrict__ part,
                                                     float* __restrict__ partials) {
  const int bid = blockIdx.x;              // 256 blocks
  const int z = bid >> 7;                  // 128 blocks per z-slice
  const int row = (bid & 127) * 64 + threadIdx.x;
  float s = 0.0f;
#pragma unroll
  for (int x = 0; x < NCHUNK; ++x)
    s += part[((size_t)(z * NCHUNK + x)) * N + row];
  float val = z ? logf(s) : log1pf(s);
#pragma unroll
  for (int m = 1; m < 64; m <<= 1) val += __shfl_xor(val, m);
  if (threadIdx.x == 0) partials[bid] = val;
}

// Kernel 4: final 256-way sum -> mean loss.
__global__ __launch_bounds__(256) void reduce2_kernel(const float* __restrict__ partials,
                                                      float* __restrict__ out) {
  const int tid = threadIdx.x;
  float v = partials[tid];
#pragma unroll
  for (int m = 1; m < 64; m <<= 1) v += __shfl_xor(v, m);
  __shared__ float sm[4];
  if ((tid & 63) == 0) sm[tid >> 6] = v;
  __syncthreads();
  if (tid == 0) out[0] = (sm[0] + sm[1] + sm[2] + sm[3]) * (1.0f / (float)N);
}

extern "C" void kernel_launch(void* const* d_in, const int* in_sizes, int n_in,
                              void* d_out, int out_size, void* d_ws, size_t ws_size,
                              hipStream_t stream) {
  const float* e = (const float*)d_in[0];
  const float* p = (const float*)d_in[1];
  const float* n = (const float*)d_in[2];

  char* w = (char*)d_ws;
  uint8_t* eb = (uint8_t*)w;                                     // 2 MB
  uint8_t* pb = eb + (size_t)N * D;                              // 2 MB
  uint8_t* nb = pb + (size_t)N * D;                              // 2 MB
  float* cbuf = (float*)(nb + (size_t)N * D);                    // 32 KB
  float* part = cbuf + N;                                        // 256 KB
  float* partials = part + (size_t)2 * NCHUNK * N;               // 1 KB

  normalize_kernel<<<N / 4, 256, 0, stream>>>(e, p, n, (uint32_t*)eb, (uint32_t*)pb,
                                              (uint32_t*)nb, cbuf);
  simexp_kernel<<<dim3(NCHUNK, N / BM, 2), 256, 0, stream>>>(eb, pb, nb, cbuf, part);
  reduce1_kernel<<<256, 64, 0, stream>>>(part, partials);
  reduce2_kernel<<<1, 256, 0, stream>>>(partials, (float*)d_out);
}

// Round 8
// 126.852 us; speedup vs baseline: 1.0801x; 1.0110x over previous
//
#include <hip/hip_runtime.h>
#include <stdint.h>

#define N 8192
#define D 256          // elements per row == bytes per fp8 row
#define INV_T 20.0f
#define LOG2E 1.44269504088896340736f
#define BM 128
#define BN 128
#define NXB 64         // col-blocks (N/BN)

typedef __attribute__((ext_vector_type(16))) float f32x16;
typedef __attribute__((ext_vector_type(4))) int i32x4;
typedef __attribute__((ext_vector_type(8))) int i32x8;

typedef __attribute__((address_space(3))) uint32_t lds_u32;
typedef __attribute__((address_space(1))) const uint32_t gbl_u32;

// Raw v_exp_f32 (2^x). Library exp2f carries a multi-instruction guard for
// |x|>~126; our args are bounded, so the raw trans op is safe (verified r5).
static __device__ __forceinline__ float fast_exp2(float x) {
  float r;
  asm("v_exp_f32 %0, %1" : "=v"(r) : "v"(x));
  return r;
}

// DPP-fused butterfly add levels (bit-identical to __shfl_xor tree, r4/r5).
#define DPP_ADD(v, ctrl)                                                      \
  ((v) + __builtin_bit_cast(float, __builtin_amdgcn_update_dpp(               \
             0, __builtin_bit_cast(int, (v)), (ctrl), 0xf, 0xf, true)))

// Kernel 1: per-row fp32 normalize -> fp8 e4m3 copies (HW cvt, OCP on gfx950);
// c[i] = (e_i . p_i)/T exact fp32. Also zeroes srow (the atomic exp-sum
// accumulator) and out -- stream-ordered before their users; replay-safe.
__global__ __launch_bounds__(256) void normalize_kernel(
    const float* __restrict__ e, const float* __restrict__ p, const float* __restrict__ n,
    uint32_t* __restrict__ eb, uint32_t* __restrict__ pb, uint32_t* __restrict__ nb,
    float* __restrict__ cbuf, float* __restrict__ srow, float* __restrict__ out) {
  const int tid = threadIdx.x;
  const int wave = tid >> 6, lane = tid & 63;
  const int row = blockIdx.x * 4 + wave;          // one wave per row

  if (tid < 8) srow[blockIdx.x * 8 + tid] = 0.0f;  // 2048 blocks x 8 = 16384
  if (blockIdx.x == 0 && tid == 0) out[0] = 0.0f;

  const float4 ev = ((const float4*)(e + (size_t)row * D))[lane];
  const float4 pv = ((const float4*)(p + (size_t)row * D))[lane];
  const float4 nv = ((const float4*)(n + (size_t)row * D))[lane];

  float sse = ev.x*ev.x + ev.y*ev.y + ev.z*ev.z + ev.w*ev.w;
  float ssp = pv.x*pv.x + pv.y*pv.y + pv.z*pv.z + pv.w*pv.w;
  float ssn = nv.x*nv.x + nv.y*nv.y + nv.z*nv.z + nv.w*nv.w;
  float dep = ev.x*pv.x + ev.y*pv.y + ev.z*pv.z + ev.w*pv.w;
#pragma unroll
  for (int m = 1; m < 64; m <<= 1) {
    sse += __shfl_xor(sse, m);
    ssp += __shfl_xor(ssp, m);
    ssn += __shfl_xor(ssn, m);
    dep += __shfl_xor(dep, m);
  }
  const float se = 1.0f / fmaxf(sqrtf(sse), 1e-8f);
  const float sp = 1.0f / fmaxf(sqrtf(ssp), 1e-8f);
  const float sn = 1.0f / fmaxf(sqrtf(ssn), 1e-8f);

  int ue = __builtin_amdgcn_cvt_pk_fp8_f32(ev.x*se, ev.y*se, 0, false);
  ue     = __builtin_amdgcn_cvt_pk_fp8_f32(ev.z*se, ev.w*se, ue, true);
  int up = __builtin_amdgcn_cvt_pk_fp8_f32(pv.x*sp, pv.y*sp, 0, false);
  up     = __builtin_amdgcn_cvt_pk_fp8_f32(pv.z*sp, pv.w*sp, up, true);
  int un = __builtin_amdgcn_cvt_pk_fp8_f32(nv.x*sn, nv.y*sn, 0, false);
  un     = __builtin_amdgcn_cvt_pk_fp8_f32(nv.z*sn, nv.w*sn, un, true);
  eb[row * 64 + lane] = (uint32_t)ue;             // 64 uints = 256 fp8 bytes per row
  pb[row * 64 + lane] = (uint32_t)up;
  nb[row * 64 + lane] = (uint32_t)un;

  if (lane == 0) cbuf[row] = dep * se * sp * INV_T;
}

// Kernel 2: 128x128-tile fp8 GEMM (X @ Y^T) with fused exp row-sums.
// Core is EXACTLY round 5 (58.4 us, VGPR 52, 0 bank conflicts, no spill):
//  - B staged full-K (32 KB, single buffer, ONE barrier) via global_load_lds,
//    16-slot XOR layout: group gg of row r at slot gg^(r&15) (read XORs again
//    -> canonical K-order; involution). Measured conflict-free.
//  - A direct to registers (8 x dwordx4 per lane; block footprint 32 KB, L1/L2).
//  - MX-scaled MFMA 32x32x64_f8f6f4 (fmt 0 = e4m3, unit scales): bit-exact vs
//    non-scaled fp8 at 2x rate. Raw v_exp_f32 + XOR-folded B addresses.
//  - 3 blocks/CU, free-drifting (no inter-tile barriers) -> pipes stay mixed.
// CHANGED (r8): epilogue accumulates into srow via global atomicAdd
// (device-scope, L2-resident 64 KB target) instead of storing a 4 MB `part`
// tensor -- removes a kernel launch + the part round-trip. Reorder noise
// ~1e-7 rel, 5 orders below the fp8-vs-fp32 error already tolerated.
__global__ __launch_bounds__(256, 3) void simexp_kernel(
    const uint8_t* __restrict__ eb, const uint8_t* __restrict__ pb,
    const uint8_t* __restrict__ nb, const float* __restrict__ cbuf,
    float* __restrict__ srow) {
  __shared__ uint8_t Bs[BN * D];    // 32 KB, full-K B tile (swizzled)
  __shared__ float cs[BM];          // 512 B

  const int z = blockIdx.z;
  const uint8_t* __restrict__ A = z ? pb : eb;
  const uint8_t* __restrict__ B = z ? eb : nb;

  const int tid = threadIdx.x;
  const int wave = tid >> 6, lane = tid & 63;
  const int lane31 = lane & 31, half = lane >> 5;
  const int rowTile = blockIdx.x * BM, colblk = blockIdx.y;
  const int colTile = colblk * BN;

  // ---- stage B (full K): 2048 16B chunks, 8 per thread, coalesced ----
#pragma unroll
  for (int i = 0; i < 8; ++i) {
    const int c = i * 256 + tid, r = c >> 4, sl = c & 15;
    const int gg = sl ^ (r & 15);               // swizzled SOURCE group
    __builtin_amdgcn_global_load_lds(
        (gbl_u32*)(B + (size_t)(colTile + r) * D + gg * 16),
        (lds_u32*)&Bs[c * 16], 16, 0, 0);
  }

  // ---- A direct to registers: this lane's row, its K-half, all 4 K-steps ----
  const int arow = rowTile + wave * 32 + lane31;
  const uint8_t* __restrict__ Arow = A + (size_t)arow * D + half * 32;
  i32x8 afr[4];
#pragma unroll
  for (int s = 0; s < 4; ++s) {
    const i32x4 lo = *(const i32x4*)(Arow + s * 64);
    const i32x4 hi = *(const i32x4*)(Arow + s * 64 + 16);
    afr[s] = (i32x8){lo[0], lo[1], lo[2], lo[3], hi[0], hi[1], hi[2], hi[3]};
  }

  if (tid < BM) cs[tid] = cbuf[rowTile + tid] * LOG2E;

  // per-ni XOR-folded B fragment base addresses (byte offsets into Bs)
  int bbase[4];
#pragma unroll
  for (int ni = 0; ni < 4; ++ni) {
    const int cl = ni * 32 + lane31;
    bbase[ni] = (cl << 8) ^ ((cl & 15) << 4) ^ (half << 5);
  }

  f32x16 acc[4];
#pragma unroll
  for (int ni = 0; ni < 4; ++ni)
#pragma unroll
    for (int r = 0; r < 16; ++r) acc[ni][r] = 0.0f;

  __syncthreads();   // the ONLY barrier: B tile + cs visible

  // ---- K loop: 4 steps of K=64, zero barriers, compiler free to pipeline ----
#pragma unroll
  for (int s = 0; s < 4; ++s) {
#pragma unroll
    for (int ni = 0; ni < 4; ++ni) {
      const int alo = bbase[ni] ^ (s << 6);     // 1 v_xor (s<<6 is inline const)
      const i32x4 blo = *(const i32x4*)&Bs[alo];
      const i32x4 bhi = *(const i32x4*)&Bs[alo ^ 16];
      const i32x8 b = (i32x8){blo[0], blo[1], blo[2], blo[3],
                              bhi[0], bhi[1], bhi[2], bhi[3]};
      acc[ni] = __builtin_amdgcn_mfma_scale_f32_32x32x64_f8f6f4(
          afr[s], b, acc[ni],
          0 /*A fmt fp8*/, 0 /*B fmt fp8*/,
          0, 0x7F7F7F7F /*scaleA=1*/, 0, 0x7F7F7F7F /*scaleB=1*/);
    }
  }

  // ---- epilogue: exp2 + row-sum over this wave's 128 cols ----
  // 32x32 C/D: col=lane&31, row=(reg&3)+8*(reg>>2)+4*(lane>>5) (m74/m101).
  const float K2 = INV_T * LOG2E;
#pragma unroll
  for (int reg = 0; reg < 16; ++reg) {
    const int rlocal = (reg & 3) + 8 * (reg >> 2) + 4 * half;
    const int rowl = wave * 32 + rlocal;
    const float cv = cs[rowl];
    float v = fast_exp2(acc[0][reg] * K2 - cv) + fast_exp2(acc[1][reg] * K2 - cv) +
              fast_exp2(acc[2][reg] * K2 - cv) + fast_exp2(acc[3][reg] * K2 - cv);
    v = DPP_ADD(v, 0xB1);    // xor1: quad_perm [1,0,3,2]
    v = DPP_ADD(v, 0x4E);    // xor2: quad_perm [2,3,0,1]
    v = DPP_ADD(v, 0x141);   // xor4: row_half_mirror
    v = DPP_ADD(v, 0x140);   // xor8: row_mirror
    v += __builtin_bit_cast(float, __builtin_amdgcn_ds_swizzle(
             __builtin_bit_cast(int, v), 0x401F));  // xor16
    if (lane31 == 0)
      atomicAdd(&srow[(size_t)z * N + rowTile + rowl], v);  // fire-and-forget
  }
}

// Kernel 3 (finalize): per-row log/log1p on the atomically-accumulated sums,
// then mean via one atomicAdd per 64-thread block (256 atomics total).
__global__ __launch_bounds__(64) void finalize_kernel(const float* __restrict__ srow,
                                                      float* __restrict__ out) {
  const int r = blockIdx.x * 64 + threadIdx.x;    // 256 blocks x 64 = 16384 rows
  const float s = srow[r];
  float val = (r >= N) ? logf(s) : log1pf(s);     // z=1 rows sit at [N, 2N)
#pragma unroll
  for (int m = 1; m < 64; m <<= 1) val += __shfl_xor(val, m);
  if (threadIdx.x == 0) atomicAdd(out, val * (1.0f / (float)N));
}

extern "C" void kernel_launch(void* const* d_in, const int* in_sizes, int n_in,
                              void* d_out, int out_size, void* d_ws, size_t ws_size,
                              hipStream_t stream) {
  const float* e = (const float*)d_in[0];
  const float* p = (const float*)d_in[1];
  const float* n = (const float*)d_in[2];

  char* w = (char*)d_ws;
  uint8_t* eb = (uint8_t*)w;                                     // 2 MB
  uint8_t* pb = eb + (size_t)N * D;                              // 2 MB
  uint8_t* nb = pb + (size_t)N * D;                              // 2 MB
  float* cbuf = (float*)(nb + (size_t)N * D);                    // 32 KB
  float* srow = cbuf + N;                                        // 64 KB (2 x N)

  normalize_kernel<<<N / 4, 256, 0, stream>>>(e, p, n, (uint32_t*)eb, (uint32_t*)pb,
                                              (uint32_t*)nb, cbuf, srow,
                                              (float*)d_out);
  simexp_kernel<<<dim3(N / BM, N / BN, 2), 256, 0, stream>>>(eb, pb, nb, cbuf, srow);
  finalize_kernel<<<256, 64, 0, stream>>>(srow, (float*)d_out);
}